// Round 1
// baseline (426.766 us; speedup 1.0000x reference)
//
#include <hip/hip_runtime.h>

// Problem constants (fixed by the reference)
#define MM 8192
#define NN 4096
#define KK 4096

// GEMM tiling
#define BM 128
#define BN 128
#define BK 64   // int8 K-chunk per LDS tile; one 16x16x64 MFMA K-step

typedef int int32x4 __attribute__((ext_vector_type(4)));

// ---------------------------------------------------------------------------
// Async global->LDS, 16B per lane. LDS destination is wave-uniform base +
// lane*16 (m104/m108); global source is per-lane free.
// ---------------------------------------------------------------------------
__device__ __forceinline__ void async_load16(const void* g, void* l) {
  __builtin_amdgcn_global_load_lds(
      (__attribute__((address_space(1))) void*)(void*)g,
      (__attribute__((address_space(3))) void*)l,
      16, 0, 0);
}

// ---------------------------------------------------------------------------
// Pack kernel: int32 (int8-range) -> int8, subtracting zero points.
// Each thread handles 16 elements: 64B read, 16B write. Exact grid cover:
//   A: M*K/16 = 2,097,152 vecs  (8192 blocks of 256)
//   W: N*K/16 = 1,048,576 vecs  (4096 blocks of 256)
// Block boundary between A and W is aligned (no intra-block divergence).
// ---------------------------------------------------------------------------
__global__ __launch_bounds__(256) void pack_kernel(
    const int* __restrict__ a, const int* __restrict__ w,
    char* __restrict__ a8, char* __restrict__ w8,
    const int* __restrict__ izp, const int* __restrict__ wzp) {
  const long tid = (long)blockIdx.x * 256 + threadIdx.x;
  const long A_VECS = (long)MM * KK / 16;

  const int4* src;
  char* dst;
  int z;
  if (tid < A_VECS) {
    src = (const int4*)a + tid * 4;
    dst = a8 + tid * 16;
    z = izp[0];
  } else {
    long t = tid - A_VECS;
    src = (const int4*)w + t * 4;
    dst = w8 + t * 16;
    z = wzp[t >> 8];  // K/16 = 256 vecs per weight row
  }

  int4 v0 = src[0], v1 = src[1], v2 = src[2], v3 = src[3];
  union { char c[16]; int4 q; } u;
  u.c[ 0]=(char)(v0.x-z); u.c[ 1]=(char)(v0.y-z); u.c[ 2]=(char)(v0.z-z); u.c[ 3]=(char)(v0.w-z);
  u.c[ 4]=(char)(v1.x-z); u.c[ 5]=(char)(v1.y-z); u.c[ 6]=(char)(v1.z-z); u.c[ 7]=(char)(v1.w-z);
  u.c[ 8]=(char)(v2.x-z); u.c[ 9]=(char)(v2.y-z); u.c[10]=(char)(v2.z-z); u.c[11]=(char)(v2.w-z);
  u.c[12]=(char)(v3.x-z); u.c[13]=(char)(v3.y-z); u.c[14]=(char)(v3.z-z); u.c[15]=(char)(v3.w-z);
  *(int4*)dst = u.q;
}

// ---------------------------------------------------------------------------
// int8 GEMM: C[m][n] = sum_k A8[m][k] * W8[n][k], then epilogue
//   out = is * ws[n] * C + bias[n]   (fp32)
//
// 128x128 block tile, 256 threads = 4 waves in 2x2, each wave 64x64 via
// 4x4 grid of v_mfma_i32_16x16x64_i8. K-loop: 4096/64 = 64 iters.
//
// LDS tiles are row-major [128][64B] with a sub-chunk XOR swizzle:
//   physical 16B sub-chunk p of row r holds logical sub-chunk p ^ ((r>>2)&3)
// implemented for free by permuting the per-lane *global* source address of
// global_load_lds. Fragment reads then hit <=2-way bank aliasing (free, m136).
// ---------------------------------------------------------------------------
__global__ __launch_bounds__(256, 2) void qgemm_kernel(
    const char* __restrict__ A8, const char* __restrict__ W8,
    float* __restrict__ out,
    const float* __restrict__ bias,
    const float* __restrict__ is_ptr,
    const float* __restrict__ wscale) {
  __shared__ __attribute__((aligned(16))) char As[BM * BK];  // 8 KB
  __shared__ __attribute__((aligned(16))) char Bs[BN * BK];  // 8 KB

  // ---- block swizzle: XCD-contiguous + grouped (GM=8) -------------------
  // grid = 64 m-tiles * 32 n-tiles = 2048 blocks; 8 XCDs round-robin.
  int pid = blockIdx.x;
  pid = (pid & 7) * 256 + (pid >> 3);      // XCD x owns pids [256x, 256x+256)
  const int group  = pid >> 8;             // /256
  const int within = pid & 255;
  const int bm = group * 8 + (within & 7); // 0..63
  const int bn = within >> 3;              // 0..31

  const int tid  = threadIdx.x;
  const int wave = tid >> 6;
  const int lane = tid & 63;
  const int wm = (wave >> 1) * 64;  // wave tile origin in block
  const int wn = (wave & 1) * 64;

  // MFMA fragment lane decomposition
  const int row_q = lane & 15;   // m/n within 16
  const int quad  = lane >> 4;   // logical k sub-chunk 0..3
  const int swz   = quad ^ (row_q >> 2);  // physical sub-chunk for frag reads

  // ---- staging addresses ------------------------------------------------
  // Wave w stages chunks {w, w+4}; chunk ch = rows [16ch, 16ch+16).
  // Lane i -> row ch*16 + (i>>2), logical sub-chunk (i&3)^((i>>4)&3).
  const int s_row = lane >> 2;                      // row within chunk, 0..15
  const int s_sub = (lane & 3) ^ ((lane >> 4) & 3); // swizzled global sub
  const long a_row0 = (long)(bm * BM + wave * 16 + s_row);
  const long a_row1 = (long)(bm * BM + (wave + 4) * 16 + s_row);
  const long b_row0 = (long)(bn * BN + wave * 16 + s_row);
  const long b_row1 = (long)(bn * BN + (wave + 4) * 16 + s_row);
  const char* a_src0 = A8 + a_row0 * KK + s_sub * 16;
  const char* a_src1 = A8 + a_row1 * KK + s_sub * 16;
  const char* b_src0 = W8 + b_row0 * KK + s_sub * 16;
  const char* b_src1 = W8 + b_row1 * KK + s_sub * 16;
  char* a_dst0 = As + wave * 1024;
  char* a_dst1 = As + (wave + 4) * 1024;
  char* b_dst0 = Bs + wave * 1024;
  char* b_dst1 = Bs + (wave + 4) * 1024;

  // fragment read base offsets (constant per lane)
  const char* a_rd = As + (wm + row_q) * BK + swz * 16;
  const char* b_rd = Bs + (wn + row_q) * BK + swz * 16;

  int32x4 acc[4][4];
#pragma unroll
  for (int mi = 0; mi < 4; ++mi)
#pragma unroll
    for (int ni = 0; ni < 4; ++ni) acc[mi][ni] = (int32x4)0;

  for (int kk = 0; kk < KK; kk += BK) {
    async_load16(a_src0 + kk, a_dst0);
    async_load16(a_src1 + kk, a_dst1);
    async_load16(b_src0 + kk, b_dst0);
    async_load16(b_src1 + kk, b_dst1);
    __syncthreads();  // compiler emits vmcnt(0) drain before s_barrier

    int32x4 afrag[4], bfrag[4];
#pragma unroll
    for (int mi = 0; mi < 4; ++mi)
      afrag[mi] = *(const int32x4*)(a_rd + mi * 16 * BK);
#pragma unroll
    for (int ni = 0; ni < 4; ++ni)
      bfrag[ni] = *(const int32x4*)(b_rd + ni * 16 * BK);

#pragma unroll
    for (int mi = 0; mi < 4; ++mi)
#pragma unroll
      for (int ni = 0; ni < 4; ++ni)
        acc[mi][ni] = __builtin_amdgcn_mfma_i32_16x16x64_i8(
            afrag[mi], bfrag[ni], acc[mi][ni], 0, 0, 0);

    __syncthreads();
  }

  // ---- epilogue: out = is * ws[n] * acc + bias[n] -----------------------
  // C/D layout (16x16): col = lane&15, row = (lane>>4)*4 + reg
  const float is0 = is_ptr[0];
  const int row_base = bm * BM + wm + quad * 4;
  const int col_base = bn * BN + wn + row_q;
#pragma unroll
  for (int ni = 0; ni < 4; ++ni) {
    const int col = col_base + ni * 16;
    const float s = is0 * wscale[col];
    const float b = bias[col];
#pragma unroll
    for (int mi = 0; mi < 4; ++mi) {
      const int row = row_base + mi * 16;
#pragma unroll
      for (int r = 0; r < 4; ++r) {
        out[(long)(row + r) * NN + col] = (float)acc[mi][ni][r] * s + b;
      }
    }
  }
}

// ---------------------------------------------------------------------------
extern "C" void kernel_launch(void* const* d_in, const int* in_sizes, int n_in,
                              void* d_out, int out_size, void* d_ws, size_t ws_size,
                              hipStream_t stream) {
  const int*   inp    = (const int*)d_in[0];    // [M,K] int32 (int8-range)
  const int*   weight = (const int*)d_in[1];    // [N,K] int32 (int8-range)
  const float* bias   = (const float*)d_in[2];  // [N]
  const float* iscale = (const float*)d_in[3];  // [1]
  const int*   izp    = (const int*)d_in[4];    // [1]
  const float* wscale = (const float*)d_in[5];  // [N]
  const int*   wzp    = (const int*)d_in[6];    // [N]
  float* out = (float*)d_out;

  char* a8 = (char*)d_ws;                        // M*K  = 33.5 MB
  char* w8 = a8 + (size_t)MM * KK;               // N*K  = 16.8 MB (total 50.3 MB)

  // pack: (M*K + N*K)/16 threads = 3,145,728 -> 12288 blocks of 256 (exact)
  pack_kernel<<<12288, 256, 0, stream>>>(inp, weight, a8, w8, izp, wzp);

  // GEMM: 64 * 32 = 2048 blocks of 256
  qgemm_kernel<<<2048, 256, 0, stream>>>(a8, w8, out, bias, iscale, wscale);
}

// Round 2
// 403.847 us; speedup vs baseline: 1.0568x; 1.0568x over previous
//
#include <hip/hip_runtime.h>

// Problem constants (fixed by the reference)
#define MM 8192
#define NN 4096
#define KK 4096

// GEMM tiling
#define BM 128
#define BN 128
#define BK 128  // int8 K-chunk per LDS tile (two 16x16x64 MFMA K-steps)

typedef int int32x4 __attribute__((ext_vector_type(4)));

// ---------------------------------------------------------------------------
// Async global->LDS, 16B per lane. LDS destination is wave-uniform base +
// lane*16 (m104/m108); global source is per-lane free.
// ---------------------------------------------------------------------------
__device__ __forceinline__ void async_load16(const void* g, void* l) {
  __builtin_amdgcn_global_load_lds(
      (__attribute__((address_space(1))) void*)(void*)g,
      (__attribute__((address_space(3))) void*)l,
      16, 0, 0);
}

// ---------------------------------------------------------------------------
// Pack kernel: int32 (int8-range) -> int8, subtracting zero points.
// 4 elements/thread: ONE int4 load (16B/lane, perfectly coalesced: wave reads
// 1 KB contiguous) -> pack -> one 4B store (wave writes 256B contiguous).
//   A: M*K/4 = 8,388,608 threads -> 32768 blocks of 256 (exact)
//   W: N*K/4 = 4,194,304 threads -> 16384 blocks of 256 (exact)
// A/W boundary is block-aligned (no intra-block divergence).
// ---------------------------------------------------------------------------
__global__ __launch_bounds__(256) void pack_kernel(
    const int* __restrict__ a, const int* __restrict__ w,
    char* __restrict__ a8, char* __restrict__ w8,
    const int* __restrict__ izp, const int* __restrict__ wzp) {
  const long tid = (long)blockIdx.x * 256 + threadIdx.x;
  const long A_T = (long)MM * KK / 4;

  const int4* src;
  int* dst;
  int z;
  if (tid < A_T) {
    src = (const int4*)a + tid;
    dst = (int*)a8 + tid;
    z = izp[0];
  } else {
    long t = tid - A_T;
    src = (const int4*)w + t;
    dst = (int*)w8 + t;
    z = wzp[t >> 10];  // K/4 = 1024 threads per weight row
  }

  int4 v = *src;
  union { char c[4]; int q; } u;
  u.c[0] = (char)(v.x - z);
  u.c[1] = (char)(v.y - z);
  u.c[2] = (char)(v.z - z);
  u.c[3] = (char)(v.w - z);
  *dst = u.q;
}

// ---------------------------------------------------------------------------
// int8 GEMM: C[m][n] = sum_k A8[m][k] * W8[n][k], then epilogue
//   out = is * ws[n] * C + bias[n]   (fp32)
//
// 128x128 block tile, BK=128 (32 K-iters), 256 threads = 4 waves in 2x2,
// each wave 64x64 via 4x4 grid of v_mfma_i32_16x16x64_i8, two K-halves per
// LDS tile. LDS = 2 x 16 KB.
//
// LDS rows are 128B = exactly 32 banks, so unswizzled rows alias perfectly.
// Swizzle: physical 16B sub-chunk p of row r holds logical p ^ (r&7),
// applied for free by permuting the per-lane *global* source address of
// global_load_lds (LDS dest of global_load_lds is fixed base+lane*16).
// Fragment reads then spread 8 lanes per 4-bank group = the 8-cycle minimum
// for a wave64 ds_read_b128.
// ---------------------------------------------------------------------------
__global__ __launch_bounds__(256, 2) void qgemm_kernel(
    const char* __restrict__ A8, const char* __restrict__ W8,
    float* __restrict__ out,
    const float* __restrict__ bias,
    const float* __restrict__ is_ptr,
    const float* __restrict__ wscale) {
  __shared__ __attribute__((aligned(16))) char As[BM * BK];  // 16 KB
  __shared__ __attribute__((aligned(16))) char Bs[BN * BK];  // 16 KB

  // ---- block swizzle: XCD-contiguous + grouped (GM=8) -------------------
  // grid = 64 m-tiles * 32 n-tiles = 2048 blocks; 8 XCDs round-robin.
  int pid = blockIdx.x;
  pid = (pid & 7) * 256 + (pid >> 3);      // XCD x owns pids [256x, 256x+256)
  const int group  = pid >> 8;             // /256
  const int within = pid & 255;
  const int bm = group * 8 + (within & 7); // 0..63
  const int bn = within >> 3;              // 0..31

  const int tid  = threadIdx.x;
  const int wave = tid >> 6;
  const int lane = tid & 63;
  const int wm = (wave >> 1) * 64;  // wave tile origin in block
  const int wn = (wave & 1) * 64;

  // ---- staging addresses ------------------------------------------------
  // A tile = 128 rows x 128B = 16 chunks of 1KB (8 rows each). Wave w stages
  // chunks {w, w+4, w+8, w+12} of A and of B.
  // Lane l -> row_in_chunk = l>>3, physical sub = l&7,
  //           logical (global) sub = (l&7) ^ (l>>3)   [since row&7 == l>>3]
  const int srow = lane >> 3;
  const int ssub = (lane & 7) ^ srow;
  const char* a_src[4];
  const char* b_src[4];
  char* a_dst[4];
  char* b_dst[4];
#pragma unroll
  for (int j = 0; j < 4; ++j) {
    const int c = wave + j * 4;  // chunk 0..15
    a_src[j] = A8 + (long)(bm * BM + c * 8 + srow) * KK + ssub * 16;
    b_src[j] = W8 + (long)(bn * BN + c * 8 + srow) * KK + ssub * 16;
    a_dst[j] = As + c * 1024;
    b_dst[j] = Bs + c * 1024;
  }

  // ---- fragment read addressing -----------------------------------------
  // MFMA 16x16x64 A-operand: lane holds m = lane&15, k = (lane>>4)*16 + j.
  // Row R = wm + mi*16 + row_q; R&7 = row_q&7 (wm, mi*16 are mult. of 8).
  // Physical sub for K-half h: (h*4 + quad) ^ (row_q&7).
  const int row_q = lane & 15;
  const int quad  = lane >> 4;
  const int psub0 = quad ^ (row_q & 7);  // h=0
  const int psub1 = psub0 ^ 4;           // h=1
  const char* a_rd = As + (wm + row_q) * BK;
  const char* b_rd = Bs + (wn + row_q) * BK;

  int32x4 acc[4][4];
#pragma unroll
  for (int mi = 0; mi < 4; ++mi)
#pragma unroll
    for (int ni = 0; ni < 4; ++ni) acc[mi][ni] = (int32x4)0;

  for (int kk = 0; kk < KK; kk += BK) {
#pragma unroll
    for (int j = 0; j < 4; ++j) {
      async_load16(a_src[j] + kk, a_dst[j]);
      async_load16(b_src[j] + kk, b_dst[j]);
    }
    __syncthreads();  // vmcnt(0) drain + barrier

#pragma unroll
    for (int h = 0; h < 2; ++h) {
      const int ps = (h == 0) ? psub0 : psub1;
      int32x4 afrag[4], bfrag[4];
#pragma unroll
      for (int mi = 0; mi < 4; ++mi)
        afrag[mi] = *(const int32x4*)(a_rd + mi * 16 * BK + ps * 16);
#pragma unroll
      for (int ni = 0; ni < 4; ++ni)
        bfrag[ni] = *(const int32x4*)(b_rd + ni * 16 * BK + ps * 16);

#pragma unroll
      for (int mi = 0; mi < 4; ++mi)
#pragma unroll
        for (int ni = 0; ni < 4; ++ni)
          acc[mi][ni] = __builtin_amdgcn_mfma_i32_16x16x64_i8(
              afrag[mi], bfrag[ni], acc[mi][ni], 0, 0, 0);
    }

    __syncthreads();
  }

  // ---- epilogue: out = is * ws[n] * acc + bias[n] -----------------------
  // C/D layout (16x16): col = lane&15, row = (lane>>4)*4 + reg
  const float is0 = is_ptr[0];
  const int row_base = bm * BM + wm + quad * 4;
  const int col_base = bn * BN + wn + row_q;
#pragma unroll
  for (int ni = 0; ni < 4; ++ni) {
    const int col = col_base + ni * 16;
    const float s = is0 * wscale[col];
    const float b = bias[col];
#pragma unroll
    for (int mi = 0; mi < 4; ++mi) {
      const int row = row_base + mi * 16;
#pragma unroll
      for (int r = 0; r < 4; ++r) {
        out[(long)(row + r) * NN + col] = (float)acc[mi][ni][r] * s + b;
      }
    }
  }
}

// ---------------------------------------------------------------------------
extern "C" void kernel_launch(void* const* d_in, const int* in_sizes, int n_in,
                              void* d_out, int out_size, void* d_ws, size_t ws_size,
                              hipStream_t stream) {
  const int*   inp    = (const int*)d_in[0];    // [M,K] int32 (int8-range)
  const int*   weight = (const int*)d_in[1];    // [N,K] int32 (int8-range)
  const float* bias   = (const float*)d_in[2];  // [N]
  const float* iscale = (const float*)d_in[3];  // [1]
  const int*   izp    = (const int*)d_in[4];    // [1]
  const float* wscale = (const float*)d_in[5];  // [N]
  const int*   wzp    = (const int*)d_in[6];    // [N]
  float* out = (float*)d_out;

  char* a8 = (char*)d_ws;                        // M*K  = 33.5 MB
  char* w8 = a8 + (size_t)MM * KK;               // N*K  = 16.8 MB (total 50.3 MB)

  // pack: (M*K + N*K)/4 threads = 12,582,912 -> 49152 blocks of 256 (exact)
  pack_kernel<<<49152, 256, 0, stream>>>(inp, weight, a8, w8, izp, wzp);

  // GEMM: 64 * 32 = 2048 blocks of 256
  qgemm_kernel<<<2048, 256, 0, stream>>>(a8, w8, out, bias, iscale, wscale);
}